// Round 22
// baseline (366.159 us; speedup 1.0000x reference)
//
#include <hip/hip_runtime.h>
#include <math.h>

#define NPOS 1024   // H*W
#define DH   32     // dim head
#define NBH  8      // B * HEADS
#define CH   256
#define INNER 128   // HEADS*DIM_HEAD
#define NWG  512    // grid size == 2 WG/CU x 256 CU (co-residency exact)

typedef __attribute__((ext_vector_type(4))) _Float16 half4;
typedef __attribute__((ext_vector_type(4))) float f32x4;

// Canonical CDNA 16x16x16 f16 MFMA.  A: row=l&15, k=4*(l>>4)+j.  B: col=l&15,
// same k ordering.  C/D: col=l&15, row=(l>>4)*4+reg.  (HW-verified R9-R21.)
#define MFMA16(a, b, c) __builtin_amdgcn_mfma_f32_16x16x16f16((a), (b), (c), 0, 0, 0)

// Fragment-tiled f16 layout (R18, passing):
//   idx(bh, t, db, lg, lr, j) = ((((bh*64 + t)*2 + db)*4 + lg)*16 + lr)*4 + j

union h2u { _Float16 h; unsigned short u; };

__device__ __forceinline__ unsigned short f2h(float f) {
  h2u c; c.h = (_Float16)f; return c.u;
}
__device__ __forceinline__ float h2f(unsigned short u) {
  h2u c; c.u = u; return (float)c.h;
}
__device__ __forceinline__ half4 ldh4(const unsigned short* __restrict__ p) {
  union { half4 v; uint2 u; } r;
  r.u = *(const uint2*)p;
  return r.v;
}
__device__ __forceinline__ void split4(const float* v, half4& hi, half4& lo) {
  unsigned short h[4], lw[4];
  #pragma unroll
  for (int j = 0; j < 4; ++j) {
    h[j]  = f2h(v[j]);
    lw[j] = f2h(v[j] - h2f(h[j]));
  }
  union { half4 v4; unsigned int u[2]; } H, L;
  H.u[0] = (unsigned int)h[0]  | ((unsigned int)h[1]  << 16);
  H.u[1] = (unsigned int)h[2]  | ((unsigned int)h[3]  << 16);
  L.u[0] = (unsigned int)lw[0] | ((unsigned int)lw[1] << 16);
  L.u[1] = (unsigned int)lw[2] | ((unsigned int)lw[3] << 16);
  hi = H.v4;  lo = L.v4;
}

// Device-scope grid barrier.  R20/R21 post-mortem: both polls compiled to an
// AGENT-scope cacheable LOAD (LLVM elides atomicAdd(p,0) into a load) which
// is served from the polling XCD's own non-coherent L2 -> progress only on
// line eviction (~350us).  Fix: SYSTEM-scope atomics -> the backend must emit
// sc0 sc1 (L1+L2 bypass) so every poll reads the coherent point.
__device__ __forceinline__ void grid_barrier(unsigned* slot) {
  __syncthreads();
  __threadfence();                     // release: phase stores visible device-wide
  if (threadIdx.x == 0) {
    __hip_atomic_fetch_add(slot, 1u, __ATOMIC_RELAXED, __HIP_MEMORY_SCOPE_SYSTEM);
    while (__hip_atomic_load(slot, __ATOMIC_RELAXED, __HIP_MEMORY_SCOPE_SYSTEM) < NWG)
      __builtin_amdgcn_s_sleep(32);    // ~2K cycles between polls
  }
  __syncthreads();
  __threadfence();                     // acquire side
}

// ---------------------------------------------------------------------------
// Single fused kernel: 512 WGs x 512 threads, 3 phases, 2 grid barriers.
// Phase bodies are verbatim R19 (passing, 30.3us as 3 kernels).
// ---------------------------------------------------------------------------
__global__ __launch_bounds__(512, 4) void fused_all(
    const float* __restrict__ x,  const float* __restrict__ Wq,
    const float* __restrict__ Wk, const float* __restrict__ Wv,
    const float* __restrict__ Wo,
    const float* __restrict__ bwp, const float* __restrict__ swp,
    const float* __restrict__ ssp, float* __restrict__ out,
    unsigned short* __restrict__ Qhi, unsigned short* __restrict__ Qlo,
    unsigned short* __restrict__ Khi, unsigned short* __restrict__ Klo,
    unsigned short* __restrict__ Vthi, unsigned short* __restrict__ Vtlo,
    float* __restrict__ Onorm, unsigned* bar)
{
  __shared__ __align__(16) char smem[19664];   // max over phases

  const int bid = blockIdx.x;
  const int tid = threadIdx.x;
  const int l   = tid & 63;
  const int wid = __builtin_amdgcn_readfirstlane(tid >> 6); // 0..7 SGPR
  const int lr  = l & 15;
  const int lg  = l >> 4;

  // ================= phase 1: QKV projection (R19 body) ===================
  {
    float (*part)[3][12][64] = (float(*)[3][12][64])smem;   // 18432 B
    const int jl = wid >> 2;         // job within WG (0..1)
    const int kq = wid & 3;          // K quarter (0..3)

    const int job   = bid * 2 + jl;  // 0..1023
    const int b     = job >> 9;
    const int itile = (job >> 6) & 7;
    const int ntile = job & 63;

    const int i_row = itile * 16 + lr;
    const int gn    = ntile * 16 + lr;

    const float* xb  = x + (size_t)b * CH * NPOS;
    const float* wqr = Wq + (size_t)i_row * CH;
    const float* wkr = Wk + (size_t)i_row * CH;
    const float* wvr = Wv + (size_t)i_row * CH;

    f32x4 aq = {0.f,0.f,0.f,0.f}, ak = {0.f,0.f,0.f,0.f}, av = {0.f,0.f,0.f,0.f};

    #pragma unroll
    for (int kk = 0; kk < 4; ++kk) {
      const int cb = kq * 64 + kk * 16 + lg * 4;

      float xv[4];
      #pragma unroll
      for (int j = 0; j < 4; ++j) xv[j] = xb[(size_t)(cb + j) * NPOS + gn];
      half4 Bhi, Blo;
      split4(xv, Bhi, Blo);

      {
        float4 wv4 = *(const float4*)(wqr + cb);
        float wv[4] = {wv4.x, wv4.y, wv4.z, wv4.w};
        half4 Ahi, Alo;  split4(wv, Ahi, Alo);
        aq = MFMA16(Ahi, Bhi, aq);
        aq = MFMA16(Ahi, Blo, aq);
        aq = MFMA16(Alo, Bhi, aq);
      }
      {
        float4 wv4 = *(const float4*)(wkr + cb);
        float wv[4] = {wv4.x, wv4.y, wv4.z, wv4.w};
        half4 Ahi, Alo;  split4(wv, Ahi, Alo);
        ak = MFMA16(Ahi, Bhi, ak);
        ak = MFMA16(Ahi, Blo, ak);
        ak = MFMA16(Alo, Bhi, ak);
      }
      {
        float4 wv4 = *(const float4*)(wvr + cb);
        float wv[4] = {wv4.x, wv4.y, wv4.z, wv4.w};
        half4 Ahi, Alo;  split4(wv, Ahi, Alo);
        av = MFMA16(Ahi, Bhi, av);
        av = MFMA16(Ahi, Blo, av);
        av = MFMA16(Alo, Bhi, av);
      }
    }

    if (kq > 0) {
      #pragma unroll
      for (int r = 0; r < 4; ++r) {
        part[jl][kq - 1][r][l]     = aq[r];
        part[jl][kq - 1][4 + r][l] = ak[r];
        part[jl][kq - 1][8 + r][l] = av[r];
      }
    }
    __syncthreads();
    if (kq == 0) {
      #pragma unroll
      for (int p = 0; p < 3; ++p)
        #pragma unroll
        for (int r = 0; r < 4; ++r) {
          aq[r] += part[jl][p][r][l];
          ak[r] += part[jl][p][4 + r][l];
          av[r] += part[jl][p][8 + r][l];
        }

      const float qs = 0.17677669529663687f;  // 1/sqrt(32)
      const int h  = itile >> 1;
      const int bh = b * 4 + h;
      const int db = itile & 1;

      unsigned short qh[4], ql[4], kh[4], kl[4], vh[4], vl[4];
      #pragma unroll
      for (int r = 0; r < 4; ++r) {
        float q = aq[r] * qs;
        qh[r] = f2h(q);   ql[r] = f2h(q - h2f(qh[r]));
        kh[r] = f2h(ak[r]); kl[r] = f2h(ak[r] - h2f(kh[r]));
        vh[r] = f2h(av[r]); vl[r] = f2h(av[r] - h2f(vh[r]));
      }

      const size_t qkb = ((((size_t)bh * 64 + ntile) * 2 + db) * 4 + lg) * 64
                       + (size_t)lr * 4;
      *(uint2*)(Qhi + qkb) = make_uint2((unsigned)qh[0] | ((unsigned)qh[1] << 16),
                                        (unsigned)qh[2] | ((unsigned)qh[3] << 16));
      *(uint2*)(Qlo + qkb) = make_uint2((unsigned)ql[0] | ((unsigned)ql[1] << 16),
                                        (unsigned)ql[2] | ((unsigned)ql[3] << 16));
      *(uint2*)(Khi + qkb) = make_uint2((unsigned)kh[0] | ((unsigned)kh[1] << 16),
                                        (unsigned)kh[2] | ((unsigned)kh[3] << 16));
      *(uint2*)(Klo + qkb) = make_uint2((unsigned)kl[0] | ((unsigned)kl[1] << 16),
                                        (unsigned)kl[2] | ((unsigned)kl[3] << 16));

      #pragma unroll
      for (int r = 0; r < 4; ++r) {
        const size_t vb = ((((size_t)bh * 64 + ntile) * 2 + db) * 4 + (lr >> 2)) * 64
                        + (size_t)(lg * 4 + r) * 4 + (lr & 3);
        Vthi[vb] = vh[r];
        Vtlo[vb] = vl[r];
      }
    }
  }

  grid_barrier(bar);          // slot 0 (line 0)

  // ================= phase 2: fused attention (R19 body) ==================
  {
    float (*DlO)[32][17] = (float(*)[32][17])smem;            // 17408 B
    float (*DlS)[4][17]  = (float(*)[4][17])(smem + 17408);   // 2176 B
    float (*tabL)[4]     = (float(*)[4])(smem + 19584);       // 80 B

    const int w   = wid;
    const int bh  = bid & 7;         // == XCD
    const int q0  = (bid >> 3) * 16;
    const int fo  = lg * 64 + lr * 4;

    const float sc = ssp[0];
    const float bw = bwp[0];

    if (tid < 20) {
      const int cell = tid >> 2, p = tid & 3;
      float C[8];
      #pragma unroll
      for (int j = 0; j < 8; ++j) C[j] = swp[j] * sc;
      float maxc = 0.f;
      #pragma unroll
      for (int j = 0; j < 8; ++j) maxc = fmaxf(maxc, fabsf(C[j]));
      const float Bnd = fabsf(bw) * 6.0f + maxc;
      float a;
      if      (p == 0) a = (C[cell] + 4.f * C[cell+1] + C[cell+2]) * (1.f / 6.f) - Bnd;
      else if (p == 1) a = (-3.f * C[cell] + 3.f * C[cell+2]) * (1.f / 6.f);
      else if (p == 2) a = (3.f * C[cell] - 6.f * C[cell+1] + 3.f * C[cell+2]) * (1.f / 6.f);
      else             a = (-C[cell] + 3.f * C[cell+1] - 3.f * C[cell+2] + C[cell+3]) * (1.f / 6.f);
      tabL[cell][p] = a;
    }
    __syncthreads();

    const size_t qtb = ((size_t)bh * 64 + (q0 >> 4)) * 512;
    const half4 Bq_h0 = ldh4(Qhi + qtb + fo);
    const half4 Bq_h1 = ldh4(Qhi + qtb + 256 + fo);
    const half4 Bq_l0 = ldh4(Qlo + qtb + fo);
    const half4 Bq_l1 = ldh4(Qlo + qtb + 256 + fo);

    f32x4 accO0 = {0.f, 0.f, 0.f, 0.f};
    f32x4 accO1 = {0.f, 0.f, 0.f, 0.f};
    float ssum = 0.f;

    #pragma unroll 2
    for (int t = 0; t < 8; ++t) {
      const int kt  = w * 8 + t;
      const size_t ktb = ((size_t)bh * 64 + kt) * 512;

      const half4 Ak_h0 = ldh4(Khi + ktb + fo);
      const half4 Ak_h1 = ldh4(Khi + ktb + 256 + fo);
      const half4 Ak_l0 = ldh4(Klo + ktb + fo);
      const half4 Ak_l1 = ldh4(Klo + ktb + 256 + fo);

      f32x4 acc = {0.f, 0.f, 0.f, 0.f};
      acc = MFMA16(Ak_h0, Bq_h0, acc);
      acc = MFMA16(Ak_h1, Bq_h1, acc);
      acc = MFMA16(Ak_h0, Bq_l0, acc);
      acc = MFMA16(Ak_h1, Bq_l1, acc);
      acc = MFMA16(Ak_l0, Bq_h0, acc);
      acc = MFMA16(Ak_l1, Bq_h1, acc);

      unsigned short ph[4];
      #pragma unroll
      for (int r = 0; r < 4; ++r) {
        float s = acc[r];
        s = fminf(fmaxf(s, -6.0f), 6.0f);
        float e   = __expf(-s);
        float sil = s * __builtin_amdgcn_rcpf(1.0f + e);
        float tt  = fmaf(s, (1.0f / 2.4f), 2.5f);
        float cf  = fminf(floorf(tt), 4.0f);
        float u   = tt - cf;
        const float4 cv = *(const float4*)tabL[(int)cf];
        float spl = fmaf(fmaf(fmaf(cv.w, u, cv.z), u, cv.y), u, cv.x);
        float kan = fmaf(bw, sil, spl);
        unsigned short pu = f2h(__expf(kan));
        ph[r] = pu;
        ssum += h2f(pu);
      }
      union { half4 v; unsigned int u[2]; } Pb;
      Pb.u[0] = (unsigned int)ph[0] | ((unsigned int)ph[1] << 16);
      Pb.u[1] = (unsigned int)ph[2] | ((unsigned int)ph[3] << 16);

      const half4 Av_h0 = ldh4(Vthi + ktb + fo);
      const half4 Av_l0 = ldh4(Vtlo + ktb + fo);
      const half4 Av_h1 = ldh4(Vthi + ktb + 256 + fo);
      const half4 Av_l1 = ldh4(Vtlo + ktb + 256 + fo);
      accO0 = MFMA16(Av_h0, Pb.v, accO0);
      accO0 = MFMA16(Av_l0, Pb.v, accO0);
      accO1 = MFMA16(Av_h1, Pb.v, accO1);
      accO1 = MFMA16(Av_l1, Pb.v, accO1);
    }

    #pragma unroll
    for (int r = 0; r < 4; ++r) {
      DlO[w][4 * lg + r][lr]      = accO0[r];
      DlO[w][16 + 4 * lg + r][lr] = accO1[r];
    }
    DlS[w][lg][lr] = ssum;
    __syncthreads();

    {
      const int q = tid & 15;
      const int d = tid >> 4;     // 0..31 (512 threads)
      float o = 0.f, sden = 0.f;
      #pragma unroll
      for (int ww = 0; ww < 8; ++ww) {
        o += DlO[ww][d][q];
        #pragma unroll
        for (int g = 0; g < 4; ++g) sden += DlS[ww][g][q];
      }
      Onorm[((size_t)bh * DH + d) * NPOS + q0 + q] = o / sden;
    }
  }

  grid_barrier(bar + 32);     // slot 1 (separate 128B line)

  // ================= phase 3: output projection (R19 math, 4 jobs/WG) =====
  {
    float (*part)[4][64] = (float(*)[4][64])smem;   // 4096 B
    const int jl = wid >> 1;         // job within WG (0..3)
    const int kh = wid & 1;          // K half (0..1), 64 i each

    const int job   = bid * 4 + jl;  // 0..2047
    const int b     = job >> 10;
    const int ctile = (job >> 6) & 15;
    const int ntile = job & 63;

    const int c_row = ctile * 16 + lr;
    const int gn    = ntile * 16 + lr;

    const float* ob = Onorm + (size_t)b * INNER * NPOS;
    const float* wr = Wo + (size_t)c_row * INNER;

    f32x4 acc = {0.f, 0.f, 0.f, 0.f};

    #pragma unroll
    for (int kk = 0; kk < 4; ++kk) {
      const int ib = kh * 64 + kk * 16 + lg * 4;

      float xv[4];
      #pragma unroll
      for (int j = 0; j < 4; ++j) xv[j] = ob[(size_t)(ib + j) * NPOS + gn];
      half4 Bhi, Blo;
      split4(xv, Bhi, Blo);

      float4 wv4 = *(const float4*)(wr + ib);
      float wv[4] = {wv4.x, wv4.y, wv4.z, wv4.w};
      half4 Ahi, Alo;
      split4(wv, Ahi, Alo);

      acc = MFMA16(Ahi, Bhi, acc);
      acc = MFMA16(Ahi, Blo, acc);
      acc = MFMA16(Alo, Bhi, acc);
    }

    if (kh == 1) {
      #pragma unroll
      for (int r = 0; r < 4; ++r) part[jl][r][l] = acc[r];
    }
    __syncthreads();
    if (kh == 0) {
      #pragma unroll
      for (int r = 0; r < 4; ++r) acc[r] += part[jl][r][l];
      #pragma unroll
      for (int r = 0; r < 4; ++r) {
        const int c = ctile * 16 + lg * 4 + r;
        out[((size_t)(b * CH + c)) * NPOS + gn] = acc[r];
      }
    }
  }
}

// ---------------------------------------------------------------------------
extern "C" void kernel_launch(void* const* d_in, const int* in_sizes, int n_in,
                              void* d_out, int out_size, void* d_ws, size_t ws_size,
                              hipStream_t stream)
{
  const float* x  = (const float*)d_in[0];
  const float* Wq = (const float*)d_in[1];
  const float* Wk = (const float*)d_in[2];
  const float* Wv = (const float*)d_in[3];
  const float* Wo = (const float*)d_in[4];
  const float* bw = (const float*)d_in[5];
  const float* sw = (const float*)d_in[6];
  const float* ss = (const float*)d_in[7];
  float* out = (float*)d_out;

  // workspace: Onorm (f32, 1MB) | 6x f16 QKV (512KB each) | barrier slots
  float* Onorm = (float*)d_ws;
  unsigned short* base = (unsigned short*)(Onorm + (size_t)NBH * DH * NPOS);
  const size_t QKN = (size_t)NBH * NPOS * DH;   // 262144 elements
  unsigned short* Qhi  = base;
  unsigned short* Qlo  = Qhi  + QKN;
  unsigned short* Khi  = Qlo  + QKN;
  unsigned short* Klo  = Khi  + QKN;
  unsigned short* Vthi = Klo  + QKN;
  unsigned short* Vtlo = Vthi + QKN;
  unsigned* bar = (unsigned*)(Vtlo + QKN);      // 2 slots on separate lines

  hipMemsetAsync(bar, 0, 256, stream);
  fused_all<<<dim3(NWG), 512, 0, stream>>>(
      x, Wq, Wk, Wv, Wo, bw, sw, ss, out,
      Qhi, Qlo, Khi, Klo, Vthi, Vtlo, Onorm, bar);
}

// Round 23
// 30.321 us; speedup vs baseline: 12.0762x; 12.0762x over previous
//
#include <hip/hip_runtime.h>
#include <math.h>

#define NPOS 1024   // H*W
#define DH   32     // dim head
#define NBH  8      // B * HEADS
#define CH   256
#define INNER 128   // HEADS*DIM_HEAD

typedef __attribute__((ext_vector_type(4))) _Float16 half4;
typedef __attribute__((ext_vector_type(4))) float f32x4;

// Canonical CDNA 16x16x16 f16 MFMA.  A: row=l&15, k=4*(l>>4)+j.  B: col=l&15,
// same k ordering.  C/D: col=l&15, row=(l>>4)*4+reg.   (HW-verified by the
// passing attn_fused kernel, R9-R19.)
#define MFMA16(a, b, c) __builtin_amdgcn_mfma_f32_16x16x16f16((a), (b), (c), 0, 0, 0)

// Fragment-tiled f16 layout (R18, passing): for each 16x16 tile,
//   idx(bh, t, db, lg, lr, j) = ((((bh*64 + t)*2 + db)*4 + lg)*16 + lr)*4 + j
// Q/K: t = n-tile, lr = row within tile, d = db*16 + lg*4 + j.
// V  : t = key tile, lr = d&15, db = d>>4, lg = (key&15)>>2, j = key&3.

union h2u { _Float16 h; unsigned short u; };

__device__ __forceinline__ unsigned short f2h(float f) {
  h2u c; c.h = (_Float16)f; return c.u;
}
__device__ __forceinline__ float h2f(unsigned short u) {
  h2u c; c.u = u; return (float)c.h;
}
__device__ __forceinline__ half4 ldh4(const unsigned short* __restrict__ p) {
  union { half4 v; uint2 u; } r;
  r.u = *(const uint2*)p;
  return r.v;
}
// build half4 fragment pair (hi, lo) from 4 f32 values
__device__ __forceinline__ void split4(const float* v, half4& hi, half4& lo) {
  unsigned short h[4], lw[4];
  #pragma unroll
  for (int j = 0; j < 4; ++j) {
    h[j]  = f2h(v[j]);
    lw[j] = f2h(v[j] - h2f(h[j]));
  }
  union { half4 v4; unsigned int u[2]; } H, L;
  H.u[0] = (unsigned int)h[0]  | ((unsigned int)h[1]  << 16);
  H.u[1] = (unsigned int)h[2]  | ((unsigned int)h[3]  << 16);
  L.u[0] = (unsigned int)lw[0] | ((unsigned int)lw[1] << 16);
  L.u[1] = (unsigned int)lw[2] | ((unsigned int)lw[3] << 16);
  hi = H.v4;  lo = L.v4;
}

// ---------------------------------------------------------------------------
// Kernel A: QKV projection as split-f16 MFMA GEMM + hi/lo encode.
// ---------------------------------------------------------------------------
__global__ __launch_bounds__(512) void proj_kernel(
    const float* __restrict__ x, const float* __restrict__ Wq,
    const float* __restrict__ Wk, const float* __restrict__ Wv,
    unsigned short* __restrict__ Qhi, unsigned short* __restrict__ Qlo,
    unsigned short* __restrict__ Khi, unsigned short* __restrict__ Klo,
    unsigned short* __restrict__ Vthi, unsigned short* __restrict__ Vtlo)
{
  __shared__ float part[2][3][12][64];   // [job-local][kq-1][acc12][lane] 18KB

  const int tid = threadIdx.x;
  const int l   = tid & 63;
  const int wid = __builtin_amdgcn_readfirstlane(tid >> 6); // 0..7 SGPR
  const int jl  = wid >> 2;        // job within WG (0..1)
  const int kq  = wid & 3;         // K quarter (0..3)

  const int job   = blockIdx.x * 2 + jl;   // 0..1023
  const int b     = job >> 9;
  const int itile = (job >> 6) & 7;
  const int ntile = job & 63;

  const int lr = l & 15;
  const int lg = l >> 4;
  const int i_row = itile * 16 + lr;       // A-operand row (W row)
  const int gn    = ntile * 16 + lr;       // B-operand col (n)

  const float* xb = x + (size_t)b * CH * NPOS;
  const float* wqr = Wq + (size_t)i_row * CH;
  const float* wkr = Wk + (size_t)i_row * CH;
  const float* wvr = Wv + (size_t)i_row * CH;

  f32x4 aq = {0.f,0.f,0.f,0.f}, ak = {0.f,0.f,0.f,0.f}, av = {0.f,0.f,0.f,0.f};

  #pragma unroll
  for (int kk = 0; kk < 4; ++kk) {
    const int cb = kq * 64 + kk * 16 + lg * 4;   // this lane's k base

    // ---- B fragment from x (4 strided loads, split f16) ----
    float xv[4];
    #pragma unroll
    for (int j = 0; j < 4; ++j) xv[j] = xb[(size_t)(cb + j) * NPOS + gn];
    half4 Bhi, Blo;
    split4(xv, Bhi, Blo);

    // ---- A fragments from W (float4 + split), 3 MFMAs each ----
    {
      float4 wv4 = *(const float4*)(wqr + cb);
      float wv[4] = {wv4.x, wv4.y, wv4.z, wv4.w};
      half4 Ahi, Alo;  split4(wv, Ahi, Alo);
      aq = MFMA16(Ahi, Bhi, aq);
      aq = MFMA16(Ahi, Blo, aq);
      aq = MFMA16(Alo, Bhi, aq);
    }
    {
      float4 wv4 = *(const float4*)(wkr + cb);
      float wv[4] = {wv4.x, wv4.y, wv4.z, wv4.w};
      half4 Ahi, Alo;  split4(wv, Ahi, Alo);
      ak = MFMA16(Ahi, Bhi, ak);
      ak = MFMA16(Ahi, Blo, ak);
      ak = MFMA16(Alo, Bhi, ak);
    }
    {
      float4 wv4 = *(const float4*)(wvr + cb);
      float wv[4] = {wv4.x, wv4.y, wv4.z, wv4.w};
      half4 Ahi, Alo;  split4(wv, Ahi, Alo);
      av = MFMA16(Ahi, Bhi, av);
      av = MFMA16(Ahi, Blo, av);
      av = MFMA16(Alo, Bhi, av);
    }
  }

  // ---- K-split combine via LDS ----
  if (kq > 0) {
    #pragma unroll
    for (int r = 0; r < 4; ++r) {
      part[jl][kq - 1][r][l]     = aq[r];
      part[jl][kq - 1][4 + r][l] = ak[r];
      part[jl][kq - 1][8 + r][l] = av[r];
    }
  }
  __syncthreads();
  if (kq > 0) return;

  #pragma unroll
  for (int p = 0; p < 3; ++p)
    #pragma unroll
    for (int r = 0; r < 4; ++r) {
      aq[r] += part[jl][p][r][l];
      ak[r] += part[jl][p][4 + r][l];
      av[r] += part[jl][p][8 + r][l];
    }

  // ---- encode hi/lo f16 and store (fragment-tiled layout) ----
  const float qs = 0.17677669529663687f;  // 1/sqrt(32)
  const int h  = itile >> 1;
  const int bh = b * 4 + h;
  const int db = itile & 1;               // d block (0: d 0-15, 1: d 16-31)

  unsigned short qh[4], ql[4], kh[4], kl[4], vh[4], vl[4];
  #pragma unroll
  for (int r = 0; r < 4; ++r) {
    float q = aq[r] * qs;
    qh[r] = f2h(q);   ql[r] = f2h(q - h2f(qh[r]));
    kh[r] = f2h(ak[r]); kl[r] = f2h(ak[r] - h2f(kh[r]));
    vh[r] = f2h(av[r]); vl[r] = f2h(av[r] - h2f(vh[r]));
  }

  // Q/K: lane (lr,lg) holds d = db*16 + lg*4 + r for row gn -> contiguous 8B
  const size_t qkb = ((((size_t)bh * 64 + ntile) * 2 + db) * 4 + lg) * 64
                   + (size_t)lr * 4;
  *(uint2*)(Qhi + qkb) = make_uint2((unsigned)qh[0] | ((unsigned)qh[1] << 16),
                                    (unsigned)qh[2] | ((unsigned)qh[3] << 16));
  *(uint2*)(Qlo + qkb) = make_uint2((unsigned)ql[0] | ((unsigned)ql[1] << 16),
                                    (unsigned)ql[2] | ((unsigned)ql[3] << 16));
  *(uint2*)(Khi + qkb) = make_uint2((unsigned)kh[0] | ((unsigned)kh[1] << 16),
                                    (unsigned)kh[2] | ((unsigned)kh[3] << 16));
  *(uint2*)(Klo + qkb) = make_uint2((unsigned)kl[0] | ((unsigned)kl[1] << 16),
                                    (unsigned)kl[2] | ((unsigned)kl[3] << 16));

  // V: transposed fragment (lr_tgt = d&15 = lg*4+r, lg_tgt = lr>>2, j = lr&3)
  #pragma unroll
  for (int r = 0; r < 4; ++r) {
    const size_t vb = ((((size_t)bh * 64 + ntile) * 2 + db) * 4 + (lr >> 2)) * 64
                    + (size_t)(lg * 4 + r) * 4 + (lr & 3);
    Vthi[vb] = vh[r];
    Vtlo[vb] = vl[r];
  }
}

// ---------------------------------------------------------------------------
// Kernel B: fully fused attention.  Fragment-tiled coalesced loads; KAN
// coefficients via conflict-free 5x4 LDS table; f16-consistent denominator.
// ---------------------------------------------------------------------------
__global__ __launch_bounds__(512) void attn_fused(
    const unsigned short* __restrict__ Qhi, const unsigned short* __restrict__ Qlo,
    const unsigned short* __restrict__ Khi, const unsigned short* __restrict__ Klo,
    const unsigned short* __restrict__ Vthi, const unsigned short* __restrict__ Vtlo,
    const float* __restrict__ bwp, const float* __restrict__ swp,
    const float* __restrict__ ssp, float* __restrict__ Onorm)
{
  __shared__ float DlO[8][32][17];
  __shared__ float DlS[8][4][17];
  __shared__ float tabL[5][4];     // per-cell cubic coeffs, -Bnd folded in a0

  const int tid = threadIdx.x;
  const int l   = tid & 63;
  const int w   = tid >> 6;        // 0..7
  const int lr  = l & 15;
  const int lg  = l >> 4;          // 0..3
  const int bh  = blockIdx.x;      // 0..7 (== XCD)
  const int q0  = blockIdx.y * 16;

  const int fo  = lg * 64 + lr * 4;   // fragment offset within a (t,db) block

  // ---- uniform KAN constants ----
  const float sc = ssp[0];
  const float bw = bwp[0];

  // build coefficient table (20 threads; same formulas as the select-chain
  // version -> identical IEEE values)
  if (tid < 20) {
    const int cell = tid >> 2, p = tid & 3;
    float C[8];
    #pragma unroll
    for (int j = 0; j < 8; ++j) C[j] = swp[j] * sc;
    float maxc = 0.f;
    #pragma unroll
    for (int j = 0; j < 8; ++j) maxc = fmaxf(maxc, fabsf(C[j]));
    const float Bnd = fabsf(bw) * 6.0f + maxc;
    float a;
    if      (p == 0) a = (C[cell] + 4.f * C[cell+1] + C[cell+2]) * (1.f / 6.f) - Bnd;
    else if (p == 1) a = (-3.f * C[cell] + 3.f * C[cell+2]) * (1.f / 6.f);
    else if (p == 2) a = (3.f * C[cell] - 6.f * C[cell+1] + 3.f * C[cell+2]) * (1.f / 6.f);
    else             a = (-C[cell] + 3.f * C[cell+1] - 3.f * C[cell+2] + C[cell+3]) * (1.f / 6.f);
    tabL[cell][p] = a;
  }
  __syncthreads();

  // ---- Q fragments (B-operand, persistent): tile t = q0>>4 ----
  const size_t qtb = ((size_t)bh * 64 + (q0 >> 4)) * 512;
  const half4 Bq_h0 = ldh4(Qhi + qtb + fo);
  const half4 Bq_h1 = ldh4(Qhi + qtb + 256 + fo);
  const half4 Bq_l0 = ldh4(Qlo + qtb + fo);
  const half4 Bq_l1 = ldh4(Qlo + qtb + 256 + fo);

  f32x4 accO0 = {0.f, 0.f, 0.f, 0.f};   // d 0..15
  f32x4 accO1 = {0.f, 0.f, 0.f, 0.f};   // d 16..31
  float ssum = 0.f;

  #pragma unroll 2
  for (int t = 0; t < 8; ++t) {
    const int kt  = w * 8 + t;              // key tile index
    const size_t ktb = ((size_t)bh * 64 + kt) * 512;

    // ---- QK: A = K fragment (coalesced 512B block reads) ----
    const half4 Ak_h0 = ldh4(Khi + ktb + fo);
    const half4 Ak_h1 = ldh4(Khi + ktb + 256 + fo);
    const half4 Ak_l0 = ldh4(Klo + ktb + fo);
    const half4 Ak_l1 = ldh4(Klo + ktb + 256 + fo);

    f32x4 acc = {0.f, 0.f, 0.f, 0.f};
    acc = MFMA16(Ak_h0, Bq_h0, acc);
    acc = MFMA16(Ak_h1, Bq_h1, acc);
    acc = MFMA16(Ak_h0, Bq_l0, acc);
    acc = MFMA16(Ak_h1, Bq_l1, acc);
    acc = MFMA16(Ak_l0, Bq_h0, acc);
    acc = MFMA16(Ak_l1, Bq_h1, acc);
    // acc[r] = S[q=q0+lr][k = kt*16 + 4*lg + r]

    // ---- KAN + exp(kan - Bnd); coefficients via LDS gather ----
    unsigned short ph[4];
    #pragma unroll
    for (int r = 0; r < 4; ++r) {
      float s = acc[r];
      s = fminf(fmaxf(s, -6.0f), 6.0f);
      float e   = __expf(-s);
      float sil = s * __builtin_amdgcn_rcpf(1.0f + e);
      float tt  = fmaf(s, (1.0f / 2.4f), 2.5f);   // (s+6)/2.4 in [0,5]
      float cf  = fminf(floorf(tt), 4.0f);
      float u   = tt - cf;
      const float4 cv = *(const float4*)tabL[(int)cf];   // ds_read_b128
      float spl = fmaf(fmaf(fmaf(cv.w, u, cv.z), u, cv.y), u, cv.x); // incl -Bnd
      float kan = fmaf(bw, sil, spl);
      unsigned short pu = f2h(__expf(kan));
      ph[r] = pu;
      ssum += h2f(pu);          // SAME rounded value PV consumes
    }
    union { half4 v; unsigned int u[2]; } Pb;
    Pb.u[0] = (unsigned int)ph[0] | ((unsigned int)ph[1] << 16);
    Pb.u[1] = (unsigned int)ph[2] | ((unsigned int)ph[3] << 16);
    // Pb is the B-operand fragment: col q = lr, k-elem j = key kt*16+4*lg+j

    // ---- PV: O^T += V^T · P^T  (A = V^T fragments, coalesced reads) ----
    const half4 Av_h0 = ldh4(Vthi + ktb + fo);         // d = lr
    const half4 Av_l0 = ldh4(Vtlo + ktb + fo);
    const half4 Av_h1 = ldh4(Vthi + ktb + 256 + fo);   // d = 16 + lr
    const half4 Av_l1 = ldh4(Vtlo + ktb + 256 + fo);
    accO0 = MFMA16(Av_h0, Pb.v, accO0);
    accO0 = MFMA16(Av_l0, Pb.v, accO0);
    accO1 = MFMA16(Av_h1, Pb.v, accO1);
    accO1 = MFMA16(Av_l1, Pb.v, accO1);
  }

  // ---- 8-way combine ----
  #pragma unroll
  for (int r = 0; r < 4; ++r) {
    DlO[w][4 * lg + r][lr]      = accO0[r];   // accO[r]: d = 4*lg+r, q = lr
    DlO[w][16 + 4 * lg + r][lr] = accO1[r];
  }
  DlS[w][lg][lr] = ssum;
  __syncthreads();

  {
    const int q = tid & 15;
    const int d = tid >> 4;     // 0..31 (512 threads)
    float o = 0.f, sden = 0.f;
    #pragma unroll
    for (int ww = 0; ww < 8; ++ww) {
      o += DlO[ww][d][q];
      #pragma unroll
      for (int g = 0; g < 4; ++g) sden += DlS[ww][g][q];
    }
    Onorm[((size_t)bh * DH + d) * NPOS + q0 + q] = o / sden;
  }
}

// ---------------------------------------------------------------------------
// Kernel C: output projection as split-f16 MFMA GEMM.
// ---------------------------------------------------------------------------
__global__ __launch_bounds__(512) void outproj_kernel(
    const float* __restrict__ Onorm, const float* __restrict__ Wo,
    float* __restrict__ out)
{
  __shared__ float part[2][3][4][64];   // [job-local][kq-1][acc][lane], 6 KB

  const int tid = threadIdx.x;
  const int l   = tid & 63;
  const int wid = __builtin_amdgcn_readfirstlane(tid >> 6); // 0..7 SGPR
  const int jl  = wid >> 2;        // job within WG (0..1)
  const int kq  = wid & 3;         // K quarter (0..3), 32 i each

  const int job   = blockIdx.x * 2 + jl;   // 0..2047
  const int b     = job >> 10;
  const int ctile = (job >> 6) & 15;
  const int ntile = job & 63;

  const int lr = l & 15;
  const int lg = l >> 4;
  const int c_row = ctile * 16 + lr;       // A-operand row (Wo row)
  const int gn    = ntile * 16 + lr;       // B-operand col (n)

  const float* ob = Onorm + (size_t)b * INNER * NPOS;
  const float* wr = Wo + (size_t)c_row * INNER;

  f32x4 acc = {0.f, 0.f, 0.f, 0.f};

  #pragma unroll
  for (int kk = 0; kk < 2; ++kk) {
    const int ib = kq * 32 + kk * 16 + lg * 4;   // this lane's i base

    float xv[4];
    #pragma unroll
    for (int j = 0; j < 4; ++j) xv[j] = ob[(size_t)(ib + j) * NPOS + gn];
    half4 Bhi, Blo;
    split4(xv, Bhi, Blo);

    float4 wv4 = *(const float4*)(wr + ib);
    float wv[4] = {wv4.x, wv4.y, wv4.z, wv4.w};
    half4 Ahi, Alo;
    split4(wv, Ahi, Alo);

    acc = MFMA16(Ahi, Bhi, acc);
    acc = MFMA16(Ahi, Blo, acc);
    acc = MFMA16(Alo, Bhi, acc);
  }

  if (kq > 0) {
    #pragma unroll
    for (int r = 0; r < 4; ++r) part[jl][kq - 1][r][l] = acc[r];
  }
  __syncthreads();
  if (kq > 0) return;

  #pragma unroll
  for (int p = 0; p < 3; ++p)
    #pragma unroll
    for (int r = 0; r < 4; ++r) acc[r] += part[jl][p][r][l];

  #pragma unroll
  for (int r = 0; r < 4; ++r) {
    const int c = ctile * 16 + lg * 4 + r;
    out[((size_t)(b * CH + c)) * NPOS + gn] = acc[r];
  }
}

// ---------------------------------------------------------------------------
extern "C" void kernel_launch(void* const* d_in, const int* in_sizes, int n_in,
                              void* d_out, int out_size, void* d_ws, size_t ws_size,
                              hipStream_t stream)
{
  const float* x  = (const float*)d_in[0];
  const float* Wq = (const float*)d_in[1];
  const float* Wk = (const float*)d_in[2];
  const float* Wv = (const float*)d_in[3];
  const float* Wo = (const float*)d_in[4];
  const float* bw = (const float*)d_in[5];
  const float* sw = (const float*)d_in[6];
  const float* ss = (const float*)d_in[7];
  float* out = (float*)d_out;

  // workspace: Onorm (f32, 1MB) | 6x f16 QKV (512KB each, fragment-tiled)
  float* Onorm = (float*)d_ws;
  unsigned short* base = (unsigned short*)(Onorm + (size_t)NBH * DH * NPOS);
  const size_t QKN = (size_t)NBH * NPOS * DH;   // 262144 elements
  unsigned short* Qhi  = base;
  unsigned short* Qlo  = Qhi  + QKN;
  unsigned short* Khi  = Qlo  + QKN;
  unsigned short* Klo  = Khi  + QKN;
  unsigned short* Vthi = Klo  + QKN;
  unsigned short* Vtlo = Vthi + QKN;

  proj_kernel<<<dim3(512), 512, 0, stream>>>(
      x, Wq, Wk, Wv, Qhi, Qlo, Khi, Klo, Vthi, Vtlo);
  attn_fused<<<dim3(8, 64), 512, 0, stream>>>(
      Qhi, Qlo, Khi, Klo, Vthi, Vtlo, bw, sw, ss, Onorm);
  outproj_kernel<<<dim3(1024), 512, 0, stream>>>(Onorm, Wo, out);
}